// Round 19
// baseline (80.324 us; speedup 1.0000x reference)
//
#include <hip/hip_runtime.h>

#define NFEAT   100000
#define NBATCH  256
#define DIM     128
#define MARGIN_F 0.5f
#define FLT_BIG 3.402823466e+38f

// ---- main geometry: 625 chunks x 160 rows = 100000 exactly; 10 F-tiles/chunk
#define NCHUNK  625
#define CROWS   160
#define NTILE   10
#define GRID    (NCHUNK * 4)              // 2500 blocks: (chunk, Mgroup)

// ---- f32 fallback geometry (R13): 1250 x 80
#define GRIDF   1250
#define RPBF    80
#define NTILEF  5

typedef __bf16 bf8_t  __attribute__((ext_vector_type(8)));
typedef short  sh8_t  __attribute__((ext_vector_type(8)));
typedef float  f32x4  __attribute__((ext_vector_type(4)));

__device__ __forceinline__ bf8_t pack8(float4 v0, float4 v1) {
  bf8_t r;
  r[0] = (__bf16)v0.x; r[1] = (__bf16)v0.y; r[2] = (__bf16)v0.z; r[3] = (__bf16)v0.w;
  r[4] = (__bf16)v1.x; r[5] = (__bf16)v1.y; r[6] = (__bf16)v1.z; r[7] = (__bf16)v1.w;
  return r;
}

template <typename VA, typename VC>
__device__ __forceinline__ auto mfma_sel(VA a, VA b, VC c, int)
    -> decltype(__builtin_amdgcn_mfma_f32_16x16x32_bf16(a, b, c, 0, 0, 0)) {
  return __builtin_amdgcn_mfma_f32_16x16x32_bf16(a, b, c, 0, 0, 0);
}
template <typename VA, typename VC>
__device__ __forceinline__ VC mfma_sel(VA a, VA b, VC c, long) {
  return __builtin_amdgcn_mfma_f32_16x16x32_bf16(
      __builtin_bit_cast(sh8_t, a), __builtin_bit_cast(sh8_t, b), c, 0, 0, 0);
}
__device__ __forceinline__ f32x4 mfma_bf16(bf8_t a, bf8_t b, f32x4 c) {
  return mfma_sel(a, b, c, 0);
}

#if defined(__has_builtin)
#if __has_builtin(__builtin_amdgcn_global_load_lds)
#define HAVE_GLLDS 1
#endif
#endif

__device__ __forceinline__ void stage16(const char* g, char* l) {
#ifdef HAVE_GLLDS
  __builtin_amdgcn_global_load_lds(
      (const __attribute__((address_space(1))) unsigned int*)g,
      (__attribute__((address_space(3))) unsigned int*)l, 16, 0, 0);
#else
  *reinterpret_cast<float4*>(l) = *reinterpret_cast<const float4*>(g);
#endif
}

// ============================================================================
// K1a: streaming f32->bf16 cast of inputs (64 KB) + features (25.6 MB) into
// d_ws. Measured R16-18: ~8us (~9 TB/s) -- this shape (many independent
// waves, no LDS/barriers, continuous stream) is the ONLY fast shape observed.
// ============================================================================
#define NG_IN   (NBATCH * DIM / 8)        // 4096 groups
#define NG_ALL  (NG_IN + NFEAT * DIM / 8)
__global__ __launch_bounds__(256) void cast_bf16(
    const float* __restrict__ inputs, const float* __restrict__ features,
    __bf16* __restrict__ inb, __bf16* __restrict__ featb,
    float* __restrict__ out)
{
  if (blockIdx.x == 0 && threadIdx.x == 0) out[0] = 0.0f;  // K2 accumulates
  const int gid    = blockIdx.x * 256 + threadIdx.x;
  const int stride = gridDim.x * 256;
  for (int i = gid; i < NG_ALL; i += stride) {
    const float* src; __bf16* dst;
    if (i < NG_IN) { src = inputs + (size_t)i * 8;             dst = inb   + (size_t)i * 8; }
    else           { src = features + (size_t)(i - NG_IN) * 8; dst = featb + (size_t)(i - NG_IN) * 8; }
    float4 v0 = *reinterpret_cast<const float4*>(src);
    float4 v1 = *reinterpret_cast<const float4*>(src + 4);
    *reinterpret_cast<bf8_t*>(dst) = pack8(v0, v1);
  }
}

// ============================================================================
// K1b (R19): INDEPENDENT-WAVE MFMA STREAMER -- zero LDS, zero barriers.
// 18 rounds of evidence: every kernel with inter-wave coupling (barrier-per-
// chunk lockstep OR starved/sunk prefetch) pinned at 42-66us with all pipes
// <20% busy (R18: 4400 cyc/iter vs ~150 issue work); the only fast kernel is
// K1a's shape. This kernel transplants that shape onto MFMA:
//   2500 blocks x 256 thr, (256,4) = 128-VGPR cap, ~16 waves/CU, NO coupling.
//   Block (chunk, Mg): 4 waves each own ONE M-tile (Mg*4+wv) and stream the
//   SAME 10 B-tiles of 16 feature rows (L1 serves the 4x reuse; featb L2
//   traffic = 4 x 25.6 MB total). Depth-2 named-buffer prefetch (bA/bB,
//   static regs, ~95 VGPR demand -> no R10-style load sinking). bf16 operands
//   direct from featb/inb: ZERO conversion in the loop.
// Per iter: 4 x global_load(16B) + 1 label + 4 chained MFMA + ~30 VALU.
// Partials [chunk][row]: block writes 256B contiguous (no cross-XCD lines).
// MFMA 16x16x32 layouts (guide §3, m89/m91-verified):
//   A: lane l holds A[m0 + (l&15)][ks*32 + (l>>4)*8 + e]
//   B: lane l holds B[ks*32 + (l>>4)*8 + e][j0 + (l&15)]  (= featb[j][k])
//   D: lane l reg r = sim[m0 + (l>>4)*4 + r][j0 + (l&15)]
// ============================================================================
__global__ __launch_bounds__(256, 4) void triplet_main(
    const __bf16* __restrict__ inb, const __bf16* __restrict__ featb,
    const int* __restrict__ targets, const int* __restrict__ flabels,
    const int* __restrict__ idx,
    float* __restrict__ ppos, float* __restrict__ pneg)
{
  const int tid   = threadIdx.x;
  const int lane  = tid & 63;
  const int wv    = tid >> 6;       // 0..3
  const int l15   = lane & 15;
  const int lg    = lane >> 4;      // 0..3
  const int blk   = blockIdx.x;
  const int chunk = blk >> 2;       // 0..624
  const int Mg    = blk & 3;        // M-group
  const int m0    = (Mg * 4 + wv) * 16;   // this wave's 16 batch rows
  const int frow0 = chunk * CROWS;        // first of 160 feature rows

  // ---- A fragments: direct bf16, once per wave (16 VGPRs)
  bf8_t afrag[4];
  {
    const char* abase = (const char*)inb + (size_t)(m0 + l15) * 256 + lg * 16;
#pragma unroll
    for (int ks = 0; ks < 4; ++ks)
      afrag[ks] = *reinterpret_cast<const bf8_t*>(abase + ks * 64);
  }

  // packed row metadata: meta = (self_gallery_row << 10) | target (lab<1024)
  int meta[4];
#pragma unroll
  for (int rr = 0; rr < 4; ++rr) {
    const int row = m0 + lg * 4 + rr;
    meta[rr] = (idx[row] << 10) | targets[row];
  }

  float minpos[4], maxneg[4];
#pragma unroll
  for (int rr = 0; rr < 4; ++rr) { minpos[rr] = FLT_BIG; maxneg[rr] = -FLT_BIG; }

  // ---- B stream: lane reads featb[frow0 + t*16 + l15][ks*32 + lg*8 ..+8]
  const char* bbase = (const char*)featb + ((size_t)frow0 + l15) * 256 + lg * 16;
  const int*  lbase = flabels + frow0 + l15;

#define LOADB(buf, labv, t)                                        \
  do {                                                             \
    const char* p_ = bbase + (size_t)(t) * 4096;                   \
    buf[0] = *reinterpret_cast<const bf8_t*>(p_);                  \
    buf[1] = *reinterpret_cast<const bf8_t*>(p_ + 64);             \
    buf[2] = *reinterpret_cast<const bf8_t*>(p_ + 128);            \
    buf[3] = *reinterpret_cast<const bf8_t*>(p_ + 192);            \
    labv = lbase[(t) * 16];                                        \
  } while (0)

#define EPILOGUE(acc, t, labj)                                     \
  do {                                                             \
    const int j_ = frow0 + (t) * 16 + l15;                         \
    _Pragma("unroll")                                              \
    for (int rr = 0; rr < 4; ++rr) {                               \
      const int  m_   = meta[rr];                                  \
      const bool same = ((labj) == (m_ & 1023));                   \
      const bool self = (j_ == (m_ >> 10));                        \
      minpos[rr] = fminf(minpos[rr], (same && !self) ? acc[rr] : FLT_BIG); \
      maxneg[rr] = fmaxf(maxneg[rr], same ? -FLT_BIG : acc[rr]);   \
    }                                                              \
  } while (0)

  // depth-2 named-buffer prefetch (all indices compile-time static)
  bf8_t bA[4], bB[4];
  int   labA, labB;
  LOADB(bA, labA, 0);
  LOADB(bB, labB, 1);

#pragma unroll
  for (int t = 0; t < NTILE; t += 2) {
    {
      f32x4 acc = {0.f, 0.f, 0.f, 0.f};
#pragma unroll
      for (int ks = 0; ks < 4; ++ks)
        acc = mfma_bf16(afrag[ks], bA[ks], acc);
      const int labj = labA;
      if (t + 2 < NTILE) LOADB(bA, labA, t + 2);   // reload after last use
      EPILOGUE(acc, t, labj);
    }
    {
      f32x4 acc = {0.f, 0.f, 0.f, 0.f};
#pragma unroll
      for (int ks = 0; ks < 4; ++ks)
        acc = mfma_bf16(afrag[ks], bB[ks], acc);
      const int labj = labB;
      if (t + 3 < NTILE) LOADB(bB, labB, t + 3);
      EPILOGUE(acc, t + 1, labj);
    }
  }
#undef LOADB
#undef EPILOGUE

  // ---- reduce across the 16-lane col group; contiguous [chunk][row] write
#pragma unroll
  for (int rr = 0; rr < 4; ++rr) {
    float mp = minpos[rr], mn = maxneg[rr];
#pragma unroll
    for (int m = 1; m < 16; m <<= 1) {
      mp = fminf(mp, __shfl_xor(mp, m, 64));
      mn = fmaxf(mn, __shfl_xor(mn, m, 64));
    }
    if (l15 == 0) {
      const int row = m0 + lg * 4 + rr;
      ppos[chunk * NBATCH + row] = mp;
      pneg[chunk * NBATCH + row] = mn;
    }
  }
}

// ============================================================================
// Fallback (ws too small): R13 f32 monolith, known-good ~43us path.
// ============================================================================
__global__ __launch_bounds__(512, 2) void triplet_partial_f32(
    const float* __restrict__ inputs, const float* __restrict__ features,
    const int* __restrict__ targets, const int* __restrict__ flabels,
    const int* __restrict__ idx,
    float* __restrict__ ppos, float* __restrict__ pneg,
    float* __restrict__ out)
{
  __shared__ char sB[RPBF * DIM * 4];

  const int tid  = threadIdx.x;
  const int lane = tid & 63;
  const int wv   = tid >> 6;
  const int l15  = lane & 15;
  const int lg   = lane >> 4;
  const int m0   = wv * 32;
  const int blk  = blockIdx.x;
  const int rowbase = blk * RPBF;

  if (blk == 0 && tid == 0) out[0] = 0.0f;

#pragma unroll
  for (int i = 0; i < NTILEF; ++i) {
    const int p    = i * 8192 + tid * 16;
    const int prow = p >> 9;
    const int scol = (p & 511) ^ ((prow & 7) << 4);
    stage16((const char*)features + (size_t)(rowbase + prow) * 512 + scol, &sB[p]);
  }

  bf8_t afrag[2][4];
#pragma unroll
  for (int mt = 0; mt < 2; ++mt) {
    const float* ap = inputs + (m0 + mt * 16 + l15) * DIM;
    float4 v0[4], v1[4];
#pragma unroll
    for (int ks = 0; ks < 4; ++ks) {
      const int k = ks * 32 + lg * 8;
      v0[ks] = *reinterpret_cast<const float4*>(ap + k);
      v1[ks] = *reinterpret_cast<const float4*>(ap + k + 4);
    }
#pragma unroll
    for (int ks = 0; ks < 4; ++ks)
      afrag[mt][ks] = pack8(v0[ks], v1[ks]);
  }

  int lab[NTILEF];
#pragma unroll
  for (int t = 0; t < NTILEF; ++t)
    lab[t] = flabels[rowbase + t * 16 + l15];

  int meta[2][4];
#pragma unroll
  for (int mt = 0; mt < 2; ++mt)
#pragma unroll
    for (int rr = 0; rr < 4; ++rr) {
      const int row = m0 + mt * 16 + lg * 4 + rr;
      meta[mt][rr] = (idx[row] << 10) | targets[row];
    }

  float minpos[2][4], maxneg[2][4];
#pragma unroll
  for (int mt = 0; mt < 2; ++mt)
#pragma unroll
    for (int rr = 0; rr < 4; ++rr) { minpos[mt][rr] = FLT_BIG; maxneg[mt][rr] = -FLT_BIG; }

  __syncthreads();

  const int swz = (l15 & 7) << 4;
#pragma unroll
  for (int t = 0; t < NTILEF; ++t) {
    const char* rbase = &sB[(t * 16 + l15) * 512];
    const int   j     = rowbase + t * 16 + l15;
    const int   labj  = lab[t];

    f32x4 acc0 = {0.f, 0.f, 0.f, 0.f};
    f32x4 acc1 = {0.f, 0.f, 0.f, 0.f};
#pragma unroll
    for (int ks = 0; ks < 4; ++ks) {
      const int o = ks * 128 + lg * 32;
      float4 v0 = *reinterpret_cast<const float4*>(rbase + ((o)      ^ swz));
      float4 v1 = *reinterpret_cast<const float4*>(rbase + ((o + 16) ^ swz));
      bf8_t bf = pack8(v0, v1);
      acc0 = mfma_bf16(afrag[0][ks], bf, acc0);
      acc1 = mfma_bf16(afrag[1][ks], bf, acc1);
    }
#pragma unroll
    for (int rr = 0; rr < 4; ++rr) {
      {
        const int  m = meta[0][rr];
        const bool same = (labj == (m & 1023));
        const bool self = (j == (m >> 10));
        minpos[0][rr] = fminf(minpos[0][rr], (same && !self) ? acc0[rr] : FLT_BIG);
        maxneg[0][rr] = fmaxf(maxneg[0][rr], same ? -FLT_BIG : acc0[rr]);
      }
      {
        const int  m = meta[1][rr];
        const bool same = (labj == (m & 1023));
        const bool self = (j == (m >> 10));
        minpos[1][rr] = fminf(minpos[1][rr], (same && !self) ? acc1[rr] : FLT_BIG);
        maxneg[1][rr] = fmaxf(maxneg[1][rr], same ? -FLT_BIG : acc1[rr]);
      }
    }
  }

#pragma unroll
  for (int mt = 0; mt < 2; ++mt)
#pragma unroll
    for (int rr = 0; rr < 4; ++rr) {
      float mp = minpos[mt][rr], mn = maxneg[mt][rr];
#pragma unroll
      for (int m = 1; m < 16; m <<= 1) {
        mp = fminf(mp, __shfl_xor(mp, m, 64));
        mn = fmaxf(mn, __shfl_xor(mn, m, 64));
      }
      if (l15 == 0) {
        const int row = m0 + mt * 16 + lg * 4 + rr;
        ppos[blk * NBATCH + row] = mp;
        pneg[blk * NBATCH + row] = mn;
      }
    }
}

// Kernel 2: one block per batch row; fold nblk partials, hinge, atomic mean.
__global__ __launch_bounds__(256) void triplet_reduce(
    const float* __restrict__ ppos, const float* __restrict__ pneg,
    float* __restrict__ out, int nblk)
{
  const int r = blockIdx.x;
  const int t = threadIdx.x;
  float mp = FLT_BIG, mn = -FLT_BIG;
  for (int b = t; b < nblk; b += 256) {
    mp = fminf(mp, ppos[b * NBATCH + r]);
    mn = fmaxf(mn, pneg[b * NBATCH + r]);
  }
#pragma unroll
  for (int m = 1; m < 64; m <<= 1) {
    mp = fminf(mp, __shfl_xor(mp, m, 64));
    mn = fmaxf(mn, __shfl_xor(mn, m, 64));
  }
  __shared__ float smp[4], smn[4];
  if ((t & 63) == 0) { smp[t >> 6] = mp; smn[t >> 6] = mn; }
  __syncthreads();
  if (t == 0) {
    mp = fminf(fminf(smp[0], smp[1]), fminf(smp[2], smp[3]));
    mn = fmaxf(fmaxf(smn[0], smn[1]), fmaxf(smn[2], smn[3]));
    float loss = mn - mp + MARGIN_F;
    loss = loss > 0.f ? loss : 0.f;
    atomicAdd(out, loss * (1.0f / NBATCH));
  }
}

extern "C" void kernel_launch(void* const* d_in, const int* in_sizes, int n_in,
                              void* d_out, int out_size, void* d_ws, size_t ws_size,
                              hipStream_t stream) {
  const float* inputs   = (const float*)d_in[0];
  const float* features = (const float*)d_in[1];
  const int*   targets  = (const int*)d_in[2];
  const int*   flabels  = (const int*)d_in[3];
  const int*   idx      = (const int*)d_in[4];
  float* out = (float*)d_out;

  const size_t featb_bytes = (size_t)NFEAT * DIM * 2;      // 25.6 MB
  const size_t inb_bytes   = (size_t)NBATCH * DIM * 2;     // 64 KB
  const size_t part_bytes  = (size_t)NCHUNK * NBATCH * 4;  // 640 KB each

  if (ws_size >= featb_bytes + inb_bytes + 2 * part_bytes) {
    __bf16* featb = (__bf16*)d_ws;
    __bf16* inb   = (__bf16*)((char*)d_ws + featb_bytes);
    float*  ppos  = (float*)((char*)d_ws + featb_bytes + inb_bytes);
    float*  pneg  = ppos + (size_t)NCHUNK * NBATCH;
    cast_bf16<<<2048, 256, 0, stream>>>(inputs, features, inb, featb, out);
    triplet_main<<<GRID, 256, 0, stream>>>(inb, featb, targets, flabels, idx, ppos, pneg);
    triplet_reduce<<<NBATCH, 256, 0, stream>>>(ppos, pneg, out, NCHUNK);
  } else {
    float* ppos = (float*)d_ws;                       // [GRIDF][256]
    float* pneg = ppos + (size_t)GRIDF * NBATCH;      // ~2.56 MB total
    triplet_partial_f32<<<GRIDF, 512, 0, stream>>>(inputs, features, targets,
                                                   flabels, idx, ppos, pneg, out);
    triplet_reduce<<<NBATCH, 256, 0, stream>>>(ppos, pneg, out, GRIDF);
  }
}

// Round 20
// 60.674 us; speedup vs baseline: 1.3239x; 1.3239x over previous
//
#include <hip/hip_runtime.h>

#define NFEAT   100000
#define NBATCH  256
#define DIM     128
#define MARGIN_F 0.5f
#define FLT_BIG 3.402823466e+38f

// ---- main geometry: 625 blocks x 160 feature rows = 100000 exactly
#define NCHUNK  625
#define CROWS   160
#define NTILE   10                 // 16-row B-tiles per block
#define GRID    NCHUNK             // one block per chunk; waves cover all M

// ---- f32 fallback geometry (R13): 1250 x 80
#define GRIDF   1250
#define RPBF    80
#define NTILEF  5

typedef __bf16 bf8_t  __attribute__((ext_vector_type(8)));
typedef short  sh8_t  __attribute__((ext_vector_type(8)));
typedef float  f32x4  __attribute__((ext_vector_type(4)));

__device__ __forceinline__ bf8_t pack8(float4 v0, float4 v1) {
  bf8_t r;
  r[0] = (__bf16)v0.x; r[1] = (__bf16)v0.y; r[2] = (__bf16)v0.z; r[3] = (__bf16)v0.w;
  r[4] = (__bf16)v1.x; r[5] = (__bf16)v1.y; r[6] = (__bf16)v1.z; r[7] = (__bf16)v1.w;
  return r;
}

template <typename VA, typename VC>
__device__ __forceinline__ auto mfma_sel(VA a, VA b, VC c, int)
    -> decltype(__builtin_amdgcn_mfma_f32_16x16x32_bf16(a, b, c, 0, 0, 0)) {
  return __builtin_amdgcn_mfma_f32_16x16x32_bf16(a, b, c, 0, 0, 0);
}
template <typename VA, typename VC>
__device__ __forceinline__ VC mfma_sel(VA a, VA b, VC c, long) {
  return __builtin_amdgcn_mfma_f32_16x16x32_bf16(
      __builtin_bit_cast(sh8_t, a), __builtin_bit_cast(sh8_t, b), c, 0, 0, 0);
}
__device__ __forceinline__ f32x4 mfma_bf16(bf8_t a, bf8_t b, f32x4 c) {
  return mfma_sel(a, b, c, 0);
}

#if defined(__has_builtin)
#if __has_builtin(__builtin_amdgcn_global_load_lds)
#define HAVE_GLLDS 1
#endif
#endif

__device__ __forceinline__ void stage16(const char* g, char* l) {
#ifdef HAVE_GLLDS
  __builtin_amdgcn_global_load_lds(
      (const __attribute__((address_space(1))) unsigned int*)g,
      (__attribute__((address_space(3))) unsigned int*)l, 16, 0, 0);
#else
  *reinterpret_cast<float4*>(l) = *reinterpret_cast<const float4*>(g);
#endif
}

// ============================================================================
// K1a: streaming f32->bf16 cast of inputs (64 KB) + features (25.6 MB) into
// d_ws. Measured R16-19: ~8us (~9 TB/s).
// ============================================================================
#define NG_IN   (NBATCH * DIM / 8)
#define NG_ALL  (NG_IN + NFEAT * DIM / 8)
__global__ __launch_bounds__(256) void cast_bf16(
    const float* __restrict__ inputs, const float* __restrict__ features,
    __bf16* __restrict__ inb, __bf16* __restrict__ featb,
    float* __restrict__ out)
{
  if (blockIdx.x == 0 && threadIdx.x == 0) out[0] = 0.0f;  // K2 accumulates
  const int gid    = blockIdx.x * 256 + threadIdx.x;
  const int stride = gridDim.x * 256;
  for (int i = gid; i < NG_ALL; i += stride) {
    const float* src; __bf16* dst;
    if (i < NG_IN) { src = inputs + (size_t)i * 8;             dst = inb   + (size_t)i * 8; }
    else           { src = features + (size_t)(i - NG_IN) * 8; dst = featb + (size_t)(i - NG_IN) * 8; }
    float4 v0 = *reinterpret_cast<const float4*>(src);
    float4 v1 = *reinterpret_cast<const float4*>(src + 4);
    *reinterpret_cast<bf8_t*>(dst) = pack8(v0, v1);
  }
}

// ============================================================================
// K1b (R20): independent-wave MFMA streamer + PINNED prefetch + full-M waves.
// R19's counters caught the 19-round culprit in the act: VGPR_Count=64 vs
// ~95 demand => the compiler SANK the depth-2 prefetch (as in R3/R10); every
// tile paid a cold L3 round trip (~440cyc x 10 iters = the invariant 4400
// cyc/iter). LDS variants lost their prefetch to vmcnt drains instead.
// Fixes:
//  (1) asm volatile("" : "+v"(...)) PIN after each load group -- the load
//      results must be in registers at that point; sinking is impossible.
//  (2) each wave owns FOUR M-tiles (block covers all 256 batch rows) ->
//      featb read exactly ONCE (R19's Mg-sibling blocks on different XCDs
//      doubled L3 fetch), and 16 MFMA per 4 loads (4x the latency cover).
// 625 blocks x 256 thr, (256,2): VGPR demand ~175 fits the 256 cap.
// Zero LDS, zero barriers. Partials [chunk][row] contiguous.
// MFMA 16x16x32 layouts (guide §3, m89/m91-verified):
//   A: lane l holds A[m0 + (l&15)][ks*32 + (l>>4)*8 + e]
//   B: lane l holds B[ks*32 + (l>>4)*8 + e][j0 + (l&15)]  (= featb[j][k])
//   D: lane l reg r = sim[m0 + (l>>4)*4 + r][j0 + (l&15)]
// ============================================================================
__global__ __launch_bounds__(256, 2) void triplet_main(
    const __bf16* __restrict__ inb, const __bf16* __restrict__ featb,
    const int* __restrict__ targets, const int* __restrict__ flabels,
    const int* __restrict__ idx,
    float* __restrict__ ppos, float* __restrict__ pneg)
{
  const int tid   = threadIdx.x;
  const int lane  = tid & 63;
  const int wv    = tid >> 6;       // 0..3: wave owns M-tiles wv*4..wv*4+3
  const int l15   = lane & 15;
  const int lg    = lane >> 4;      // 0..3
  const int chunk = blockIdx.x;     // 0..624
  const int m0    = wv * 64;        // first of this wave's 64 batch rows
  const int frow0 = chunk * CROWS;  // first of 160 feature rows

  // ---- A fragments: direct bf16, once per wave (4 M-tiles, 64 VGPRs)
  bf8_t afrag[4][4];
#pragma unroll
  for (int mt = 0; mt < 4; ++mt) {
    const char* abase = (const char*)inb + (size_t)(m0 + mt * 16 + l15) * 256 + lg * 16;
#pragma unroll
    for (int ks = 0; ks < 4; ++ks)
      afrag[mt][ks] = *reinterpret_cast<const bf8_t*>(abase + ks * 64);
  }

  // packed row metadata: meta = (self_gallery_row << 10) | target (lab<1024)
  int meta[4][4];
#pragma unroll
  for (int mt = 0; mt < 4; ++mt)
#pragma unroll
    for (int rr = 0; rr < 4; ++rr) {
      const int row = m0 + mt * 16 + lg * 4 + rr;
      meta[mt][rr] = (idx[row] << 10) | targets[row];
    }

  float minpos[4][4], maxneg[4][4];
#pragma unroll
  for (int mt = 0; mt < 4; ++mt)
#pragma unroll
    for (int rr = 0; rr < 4; ++rr) { minpos[mt][rr] = FLT_BIG; maxneg[mt][rr] = -FLT_BIG; }

  // ---- B stream: lane reads featb[frow0 + t*16 + l15][ks*32 + lg*8 ..+8]
  const char* bbase = (const char*)featb + ((size_t)frow0 + l15) * 256 + lg * 16;
  const int*  lbase = flabels + frow0 + l15;

#define LOADB(buf, labv, t)                                        \
  do {                                                             \
    const char* p_ = bbase + (size_t)(t) * 4096;                   \
    buf[0] = *reinterpret_cast<const bf8_t*>(p_);                  \
    buf[1] = *reinterpret_cast<const bf8_t*>(p_ + 64);             \
    buf[2] = *reinterpret_cast<const bf8_t*>(p_ + 128);            \
    buf[3] = *reinterpret_cast<const bf8_t*>(p_ + 192);            \
    labv = lbase[(t) * 16];                                        \
  } while (0)

  // PIN: force the loaded values live-in-registers HERE -- the compiler
  // cannot sink the loads past this point (R19: it silently did, VGPR=64).
#define PIN(buf, labv)                                             \
  asm volatile("" : "+v"(buf[0]), "+v"(buf[1]), "+v"(buf[2]),      \
                    "+v"(buf[3]), "+v"(labv))

#define TILE_COMPUTE(buf, labj, t)                                 \
  do {                                                             \
    f32x4 acc[4];                                                  \
    _Pragma("unroll")                                              \
    for (int mt = 0; mt < 4; ++mt) {                               \
      acc[mt] = (f32x4){0.f, 0.f, 0.f, 0.f};                       \
      _Pragma("unroll")                                            \
      for (int ks = 0; ks < 4; ++ks)                               \
        acc[mt] = mfma_bf16(afrag[mt][ks], buf[ks], acc[mt]);      \
    }                                                              \
    const int j_ = frow0 + (t) * 16 + l15;                         \
    _Pragma("unroll")                                              \
    for (int mt = 0; mt < 4; ++mt)                                 \
      _Pragma("unroll")                                            \
      for (int rr = 0; rr < 4; ++rr) {                             \
        const int  m_   = meta[mt][rr];                            \
        const bool same = ((labj) == (m_ & 1023));                 \
        const bool self = (j_ == (m_ >> 10));                      \
        minpos[mt][rr] = fminf(minpos[mt][rr],                     \
                               (same && !self) ? acc[mt][rr] : FLT_BIG); \
        maxneg[mt][rr] = fmaxf(maxneg[mt][rr],                     \
                               same ? -FLT_BIG : acc[mt][rr]);     \
      }                                                            \
  } while (0)

  // depth-2 named-buffer prefetch, pinned
  bf8_t bA[4], bB[4];
  int   labA, labB;
  LOADB(bA, labA, 0); PIN(bA, labA);
  LOADB(bB, labB, 1); PIN(bB, labB);

#pragma unroll
  for (int t = 0; t < NTILE; t += 2) {
    {
      const int labj = labA;
      // compute consumes bA; then refill bA for t+2 and pin it
      TILE_COMPUTE(bA, labj, t);
      if (t + 2 < NTILE) { LOADB(bA, labA, t + 2); PIN(bA, labA); }
    }
    {
      const int labj = labB;
      TILE_COMPUTE(bB, labj, t + 1);
      if (t + 3 < NTILE) { LOADB(bB, labB, t + 3); PIN(bB, labB); }
    }
  }
#undef LOADB
#undef PIN
#undef TILE_COMPUTE

  // ---- reduce across the 16-lane col group; contiguous [chunk][row] write
#pragma unroll
  for (int mt = 0; mt < 4; ++mt)
#pragma unroll
    for (int rr = 0; rr < 4; ++rr) {
      float mp = minpos[mt][rr], mn = maxneg[mt][rr];
#pragma unroll
      for (int m = 1; m < 16; m <<= 1) {
        mp = fminf(mp, __shfl_xor(mp, m, 64));
        mn = fmaxf(mn, __shfl_xor(mn, m, 64));
      }
      if (l15 == 0) {
        const int row = m0 + mt * 16 + lg * 4 + rr;
        ppos[chunk * NBATCH + row] = mp;
        pneg[chunk * NBATCH + row] = mn;
      }
    }
}

// ============================================================================
// Fallback (ws too small): R13 f32 monolith, known-good ~43us path.
// ============================================================================
__global__ __launch_bounds__(512, 2) void triplet_partial_f32(
    const float* __restrict__ inputs, const float* __restrict__ features,
    const int* __restrict__ targets, const int* __restrict__ flabels,
    const int* __restrict__ idx,
    float* __restrict__ ppos, float* __restrict__ pneg,
    float* __restrict__ out)
{
  __shared__ char sB[RPBF * DIM * 4];

  const int tid  = threadIdx.x;
  const int lane = tid & 63;
  const int wv   = tid >> 6;
  const int l15  = lane & 15;
  const int lg   = lane >> 4;
  const int m0   = wv * 32;
  const int blk  = blockIdx.x;
  const int rowbase = blk * RPBF;

  if (blk == 0 && tid == 0) out[0] = 0.0f;

#pragma unroll
  for (int i = 0; i < NTILEF; ++i) {
    const int p    = i * 8192 + tid * 16;
    const int prow = p >> 9;
    const int scol = (p & 511) ^ ((prow & 7) << 4);
    stage16((const char*)features + (size_t)(rowbase + prow) * 512 + scol, &sB[p]);
  }

  bf8_t afrag[2][4];
#pragma unroll
  for (int mt = 0; mt < 2; ++mt) {
    const float* ap = inputs + (m0 + mt * 16 + l15) * DIM;
    float4 v0[4], v1[4];
#pragma unroll
    for (int ks = 0; ks < 4; ++ks) {
      const int k = ks * 32 + lg * 8;
      v0[ks] = *reinterpret_cast<const float4*>(ap + k);
      v1[ks] = *reinterpret_cast<const float4*>(ap + k + 4);
    }
#pragma unroll
    for (int ks = 0; ks < 4; ++ks)
      afrag[mt][ks] = pack8(v0[ks], v1[ks]);
  }

  int lab[NTILEF];
#pragma unroll
  for (int t = 0; t < NTILEF; ++t)
    lab[t] = flabels[rowbase + t * 16 + l15];

  int meta[2][4];
#pragma unroll
  for (int mt = 0; mt < 2; ++mt)
#pragma unroll
    for (int rr = 0; rr < 4; ++rr) {
      const int row = m0 + mt * 16 + lg * 4 + rr;
      meta[mt][rr] = (idx[row] << 10) | targets[row];
    }

  float minpos[2][4], maxneg[2][4];
#pragma unroll
  for (int mt = 0; mt < 2; ++mt)
#pragma unroll
    for (int rr = 0; rr < 4; ++rr) { minpos[mt][rr] = FLT_BIG; maxneg[mt][rr] = -FLT_BIG; }

  __syncthreads();

  const int swz = (l15 & 7) << 4;
#pragma unroll
  for (int t = 0; t < NTILEF; ++t) {
    const char* rbase = &sB[(t * 16 + l15) * 512];
    const int   j     = rowbase + t * 16 + l15;
    const int   labj  = lab[t];

    f32x4 acc0 = {0.f, 0.f, 0.f, 0.f};
    f32x4 acc1 = {0.f, 0.f, 0.f, 0.f};
#pragma unroll
    for (int ks = 0; ks < 4; ++ks) {
      const int o = ks * 128 + lg * 32;
      float4 v0 = *reinterpret_cast<const float4*>(rbase + ((o)      ^ swz));
      float4 v1 = *reinterpret_cast<const float4*>(rbase + ((o + 16) ^ swz));
      bf8_t bf = pack8(v0, v1);
      acc0 = mfma_bf16(afrag[0][ks], bf, acc0);
      acc1 = mfma_bf16(afrag[1][ks], bf, acc1);
    }
#pragma unroll
    for (int rr = 0; rr < 4; ++rr) {
      {
        const int  m = meta[0][rr];
        const bool same = (labj == (m & 1023));
        const bool self = (j == (m >> 10));
        minpos[0][rr] = fminf(minpos[0][rr], (same && !self) ? acc0[rr] : FLT_BIG);
        maxneg[0][rr] = fmaxf(maxneg[0][rr], same ? -FLT_BIG : acc0[rr]);
      }
      {
        const int  m = meta[1][rr];
        const bool same = (labj == (m & 1023));
        const bool self = (j == (m >> 10));
        minpos[1][rr] = fminf(minpos[1][rr], (same && !self) ? acc1[rr] : FLT_BIG);
        maxneg[1][rr] = fmaxf(maxneg[1][rr], same ? -FLT_BIG : acc1[rr]);
      }
    }
  }

#pragma unroll
  for (int mt = 0; mt < 2; ++mt)
#pragma unroll
    for (int rr = 0; rr < 4; ++rr) {
      float mp = minpos[mt][rr], mn = maxneg[mt][rr];
#pragma unroll
      for (int m = 1; m < 16; m <<= 1) {
        mp = fminf(mp, __shfl_xor(mp, m, 64));
        mn = fmaxf(mn, __shfl_xor(mn, m, 64));
      }
      if (l15 == 0) {
        const int row = m0 + mt * 16 + lg * 4 + rr;
        ppos[blk * NBATCH + row] = mp;
        pneg[blk * NBATCH + row] = mn;
      }
    }
}

// Kernel 2: one block per batch row; fold nblk partials, hinge, atomic mean.
__global__ __launch_bounds__(256) void triplet_reduce(
    const float* __restrict__ ppos, const float* __restrict__ pneg,
    float* __restrict__ out, int nblk)
{
  const int r = blockIdx.x;
  const int t = threadIdx.x;
  float mp = FLT_BIG, mn = -FLT_BIG;
  for (int b = t; b < nblk; b += 256) {
    mp = fminf(mp, ppos[b * NBATCH + r]);
    mn = fmaxf(mn, pneg[b * NBATCH + r]);
  }
#pragma unroll
  for (int m = 1; m < 64; m <<= 1) {
    mp = fminf(mp, __shfl_xor(mp, m, 64));
    mn = fmaxf(mn, __shfl_xor(mn, m, 64));
  }
  __shared__ float smp[4], smn[4];
  if ((t & 63) == 0) { smp[t >> 6] = mp; smn[t >> 6] = mn; }
  __syncthreads();
  if (t == 0) {
    mp = fminf(fminf(smp[0], smp[1]), fminf(smp[2], smp[3]));
    mn = fmaxf(fmaxf(smn[0], smn[1]), fmaxf(smn[2], smn[3]));
    float loss = mn - mp + MARGIN_F;
    loss = loss > 0.f ? loss : 0.f;
    atomicAdd(out, loss * (1.0f / NBATCH));
  }
}

extern "C" void kernel_launch(void* const* d_in, const int* in_sizes, int n_in,
                              void* d_out, int out_size, void* d_ws, size_t ws_size,
                              hipStream_t stream) {
  const float* inputs   = (const float*)d_in[0];
  const float* features = (const float*)d_in[1];
  const int*   targets  = (const int*)d_in[2];
  const int*   flabels  = (const int*)d_in[3];
  const int*   idx      = (const int*)d_in[4];
  float* out = (float*)d_out;

  const size_t featb_bytes = (size_t)NFEAT * DIM * 2;      // 25.6 MB
  const size_t inb_bytes   = (size_t)NBATCH * DIM * 2;     // 64 KB
  const size_t part_bytes  = (size_t)NCHUNK * NBATCH * 4;  // 640 KB each

  if (ws_size >= featb_bytes + inb_bytes + 2 * part_bytes) {
    __bf16* featb = (__bf16*)d_ws;
    __bf16* inb   = (__bf16*)((char*)d_ws + featb_bytes);
    float*  ppos  = (float*)((char*)d_ws + featb_bytes + inb_bytes);
    float*  pneg  = ppos + (size_t)NCHUNK * NBATCH;
    cast_bf16<<<2048, 256, 0, stream>>>(inputs, features, inb, featb, out);
    triplet_main<<<GRID, 256, 0, stream>>>(inb, featb, targets, flabels, idx, ppos, pneg);
    triplet_reduce<<<NBATCH, 256, 0, stream>>>(ppos, pneg, out, NCHUNK);
  } else {
    float* ppos = (float*)d_ws;                       // [GRIDF][256]
    float* pneg = ppos + (size_t)GRIDF * NBATCH;      // ~2.56 MB total
    triplet_partial_f32<<<GRIDF, 512, 0, stream>>>(inputs, features, targets,
                                                   flabels, idx, ppos, pneg, out);
    triplet_reduce<<<NBATCH, 256, 0, stream>>>(ppos, pneg, out, GRIDF);
  }
}